// Round 6
// baseline (1048.933 us; speedup 1.0000x reference)
//
#include <hip/hip_runtime.h>

// ---------------------------------------------------------------------------
// Swin block on MI355X. Inputs/outputs f32; internal activations/weights bf16
// (u16), f32 accumulate in MFMA. Round 8: fused MLP v5 -- 64x64 per-wave
// register blocking (0.5 LDS reads/MFMA, was 0.75), A-operands (z) loaded
// global->VGPR (no zS staging), 32 fat pipeline steps (was 64) with 32 KB
// weight tiles double-buffered and counted vmcnt. LDS 128KB = hc 64K + 2x32K.
// ---------------------------------------------------------------------------

typedef unsigned short u16;
typedef __attribute__((ext_vector_type(8))) short bfrag8;     // 8 bf16 = 4 VGPRs
typedef __attribute__((ext_vector_type(8))) unsigned short u16x8;
typedef __attribute__((ext_vector_type(4))) float f32x4;

#define WS_TOK 49
#define C_DIM 256
#define M_ROWS 100352        // 32 * 56 * 56
#define N_WIN 2048           // 32 * 64
#define SCALE_Q 0.17677669529663689f

#if defined(__has_builtin)
#  if __has_builtin(__builtin_amdgcn_global_load_lds)
#    define HAVE_GLL 1
#  endif
#endif
#ifndef HAVE_GLL
#  define HAVE_GLL 0
#endif

__device__ __forceinline__ float u2f(u16 u) {
    union { unsigned int i; float f; } c; c.i = ((unsigned int)u) << 16; return c.f;
}
__device__ __forceinline__ u16 f2u(float f) {
    union { float f; unsigned int i; } c; c.f = f;
    unsigned int i = c.i;
    return (u16)((i + 0x7fffu + ((i >> 16) & 1u)) >> 16);   // RNE
}
__device__ __forceinline__ int regionOf(int h) {           // shift-mask region id
    return h < 49 ? 0 : (h < 53 ? 1 : 2);                  // 0:-7 / -7:-3 / -3:
}
// gelu_tanh(v) == v * sigmoid(1.5957691*(v + 0.044715 v^3)); 8 VALU ops.
__device__ __forceinline__ float gelu_fast(float v) {
    const float v2 = v * v;
    const float u = v * __builtin_fmaf(-0.0713548162f, v2, -1.5957691216f);
    const float e = __expf(u);                              // exp(-2y)
    return v * __builtin_amdgcn_rcpf(1.f + e);
}

__device__ __forceinline__ void g2l16(const u16* g, u16* l) {
#if HAVE_GLL
    __builtin_amdgcn_global_load_lds((const __attribute__((address_space(1))) void*)g,
                                     (__attribute__((address_space(3))) void*)l, 16, 0, 0);
#else
    *(bfrag8*)l = *(const bfrag8*)g;
#endif
}

// --------------------- weight transpose + f32->bf16 cast -------------------
__global__ void transpose_k(const float* __restrict__ in, u16* __restrict__ out,
                            int R, int Ccols) {
    int i = blockIdx.x * 256 + threadIdx.x;
    if (i < R * Ccols) {
        int r = i / Ccols, c = i - r * Ccols;
        out[(size_t)c * R + r] = f2u(in[i]);
    }
}

// ------------- LayerNorm f32->bf16 (mode0: +shift+window gather) -----------
__global__ __launch_bounds__(256) void ln_kernel(const float* __restrict__ xin,
                                                 const float* __restrict__ g,
                                                 const float* __restrict__ b,
                                                 u16* __restrict__ out, int mode) {
    const int w = threadIdx.x >> 6, lane = threadIdx.x & 63;
    const int r = blockIdx.x * 4 + w;   // destination row (windowed order in mode0)
    int s = r;
    if (mode == 0) {
        const int win = r / WS_TOK, tok = r - win * WS_TOK;
        const int b_ = win >> 6, w64 = win & 63;
        const int wr = w64 >> 3, wc = w64 & 7;
        const int th = tok / 7, tw = tok - th * 7;
        int hh = wr * 7 + th + 3; if (hh >= 56) hh -= 56;   // roll(-3) gather
        int ww = wc * 7 + tw + 3; if (ww >= 56) ww -= 56;
        s = b_ * 3136 + hh * 56 + ww;
    }
    const float4 u = *(const float4*)(xin + (size_t)s * C_DIM + lane * 4);
    float f0 = u.x, f1 = u.y, f2 = u.z, f3 = u.w;
    float s1 = f0 + f1 + f2 + f3;
    float s2 = f0 * f0 + f1 * f1 + f2 * f2 + f3 * f3;
#pragma unroll
    for (int off = 32; off; off >>= 1) {
        s1 += __shfl_xor(s1, off, 64);
        s2 += __shfl_xor(s2, off, 64);
    }
    const float mu = s1 * (1.f / 256.f);
    const float rs = rsqrtf(s2 * (1.f / 256.f) - mu * mu + 1e-5f);
    const float4 ug = *(const float4*)(g + lane * 4);
    const float4 ub = *(const float4*)(b + lane * 4);
    ushort4 o;
    o.x = f2u((f0 - mu) * rs * ug.x + ub.x);
    o.y = f2u((f1 - mu) * rs * ug.y + ub.y);
    o.z = f2u((f2 - mu) * rs * ug.z + ub.z);
    o.w = f2u((f3 - mu) * rs * ug.w + ub.w);
    *(ushort4*)(out + (size_t)r * C_DIM + lane * 4) = o;
}

// ------------------------------- GEMM --------------------------------------
// C(M,N) = A(M,K) @ Bt(N,K)^T ; 128x128 tile, BK=32, 4 waves in 2x2.
// 1D grid, A-tile-major swizzle: bx = bid/NY (NY consecutive blocks share A).
// Epilogue: per-wave LDS transpose (stride 68 floats: 16B-aligned reads,
// <=2-way write conflicts) -> each lane holds 16 contiguous cols of one row.
// EPI 0: qkv scatter (bf16, ushort8)  1: proj+reverse+residual (f32, float4)
template <int KD, int ND, int NY, int EPI>
__global__ __launch_bounds__(256) void gemm_bt(const u16* __restrict__ A,
                                               const u16* __restrict__ Bt,
                                               const float* __restrict__ bias,
                                               u16* __restrict__ o0,
                                               u16* __restrict__ o1,
                                               u16* __restrict__ o2,
                                               float* __restrict__ fo,
                                               const float* __restrict__ res) {
    __shared__ __align__(16) char pool[17408];      // As(8K)+Bs(8K) / Ts(17408)
    u16* As = (u16*)pool;
    u16* Bs = (u16*)(pool + 8192);
    const int tid = threadIdx.x;
    const int bid = blockIdx.x;
    const int m0 = (bid / NY) * 128;
    const int n0 = (bid % NY) * 128;
    const int wid = tid >> 6, lane = tid & 63;
    const int wy = wid >> 1, wx = wid & 1;
    const int l15 = lane & 15, lsel = lane >> 4;

    f32x4 acc[4][4] = {};
    const u16* Ag = A + (size_t)m0 * KD;
    const u16* Bg = Bt + (size_t)n0 * KD;

    for (int k0 = 0; k0 < KD; k0 += 32) {
#pragma unroll
        for (int p = 0; p < 2; ++p) {
            const int idx = p * 256 + tid;
            const int row = idx >> 2, ks = (idx & 3) << 3;
            g2l16(Ag + (size_t)row * KD + k0 + ks, As + idx * 8);
            g2l16(Bg + (size_t)row * KD + k0 + ks, Bs + idx * 8);
        }
        __syncthreads();
        bfrag8 af[4], bfv[4];
#pragma unroll
        for (int m = 0; m < 4; ++m)
            af[m] = *(const bfrag8*)(As + (wy * 64 + m * 16 + l15) * 32 + lsel * 8);
#pragma unroll
        for (int n = 0; n < 4; ++n)
            bfv[n] = *(const bfrag8*)(Bs + (wx * 64 + n * 16 + l15) * 32 + lsel * 8);
#pragma unroll
        for (int m = 0; m < 4; ++m)
#pragma unroll
            for (int n = 0; n < 4; ++n)
                acc[m][n] = __builtin_amdgcn_mfma_f32_16x16x32_bf16(af[m], bfv[n],
                                                                    acc[m][n], 0, 0, 0);
        __syncthreads();
    }

    // ---------------- epilogue: per-wave LDS transpose ----------------
    float* Ts = (float*)pool + wid * (16 * 68);     // 4352 B per wave
    const int r  = lane >> 2;                       // output row within strip
    const int cg = (lane & 3) << 4;                 // 16-col group start

#pragma unroll
    for (int m = 0; m < 4; ++m) {
#pragma unroll
        for (int n = 0; n < 4; ++n)
#pragma unroll
            for (int reg = 0; reg < 4; ++reg)
                Ts[(lsel * 4 + reg) * 68 + n * 16 + l15] = acc[m][n][reg];
        // wave-internal write->read: compiler inserts lgkmcnt wait
        float vals[16];
#pragma unroll
        for (int j = 0; j < 4; ++j)
            *(f32x4*)(vals + 4 * j) = *(const f32x4*)(Ts + r * 68 + cg + 4 * j);

        const int gr  = m0 + wy * 64 + m * 16 + r;
        const int gc0 = n0 + wx * 64 + cg;
        float bias16[16];
#pragma unroll
        for (int j = 0; j < 4; ++j)
            *(f32x4*)(bias16 + 4 * j) = *(const f32x4*)(bias + gc0 + 4 * j);

        if (EPI == 0) {
            const int win = gr / WS_TOK, tok = gr - win * WS_TOK;
            const int part = gc0 >> 8, head = (gc0 >> 5) & 7, hd = gc0 & 31;
            u16* dst = (part == 0) ? o0 : (part == 1) ? o1 : o2;
            const float sc = (part == 0) ? SCALE_Q : 1.f;
            const size_t di = (size_t)win * 8 * (WS_TOK * 32) + (size_t)tok * 32 +
                              (size_t)head * (WS_TOK * 32) + hd;
            u16x8 pk[2];
#pragma unroll
            for (int j = 0; j < 16; ++j)
                ((u16*)pk)[j] = f2u((vals[j] + bias16[j]) * sc);
            *(u16x8*)(dst + di)     = pk[0];
            *(u16x8*)(dst + di + 8) = pk[1];
        } else if (EPI == 1) {
            const int win = gr / WS_TOK, tok = gr - win * WS_TOK;
            const int b_ = win >> 6, w64 = win & 63;
            const int wr = w64 >> 3, wc = w64 & 7;
            const int th = tok / 7, tw = tok - th * 7;
            int hh = wr * 7 + th + 3; if (hh >= 56) hh -= 56;  // roll(+3) scatter
            int ww = wc * 7 + tw + 3; if (ww >= 56) ww -= 56;
            const size_t di = ((size_t)b_ * 3136 + hh * 56 + ww) * C_DIM + gc0;
#pragma unroll
            for (int j = 0; j < 4; ++j) {
                f32x4 rr = *(const f32x4*)(res + di + 4 * j);
                f32x4 o;
#pragma unroll
                for (int e = 0; e < 4; ++e)
                    o[e] = rr[e] + vals[4 * j + e] + bias16[4 * j + e];
                *(f32x4*)(fo + di + 4 * j) = o;
            }
        } else if (EPI == 2) {
            u16x8 pk[2];
#pragma unroll
            for (int j = 0; j < 16; ++j)
                ((u16*)pk)[j] = f2u(gelu_fast(vals[j] + bias16[j]));
            u16* dst = o0 + (size_t)gr * ND + gc0;
            *(u16x8*)dst       = pk[0];
            *(u16x8*)(dst + 8) = pk[1];
        } else {
            const size_t di = (size_t)gr * ND + gc0;
#pragma unroll
            for (int j = 0; j < 4; ++j) {
                f32x4 rr = *(const f32x4*)(res + di + 4 * j);
                f32x4 o;
#pragma unroll
                for (int e = 0; e < 4; ++e)
                    o[e] = rr[e] + vals[4 * j + e] + bias16[4 * j + e];
                *(f32x4*)(fo + di + 4 * j) = o;
            }
        }
    }
}

// --------------------------- fused MLP v5 ----------------------------------
// out += GELU(z @ w1T^T + b1) @ w2T^T + b2; h never leaves LDS.
// 512 thr / 8 waves (2 wy x 4 wx), wave tile 64x64, block 128 rows.
// 4 kc chunks of 256 hcols; per kc: 4 A-steps (BK=64) + 4 B-steps (BK=64).
// A-operands from GLOBAL (z, L2-hot, 8 dwordx4/wave/step); B-operands from a
// 32KB weight tile staged 1-ahead into 2x32KB double buffer (counted vmcnt:
// A-steps vmcnt(12) keeps zf8+stage4 in flight; B-steps vmcnt(4); tail 0).
// 32 MFMA per wave per step. hc[128][256] bf16 XOR-swizzled (64 KB).
__device__ __forceinline__ void stage32(const u16* __restrict__ base, int rstride,
                                        u16* dst, int tid) {
#pragma unroll
    for (int p = 0; p < 4; ++p) {                   // [256 rows][64 k] = 32 KB
        const int i = p * 512 + tid;
        const int row = i >> 3, s = i & 7;
        g2l16(base + (size_t)row * rstride + ((s ^ (row & 7)) << 3), dst + i * 8);
    }
}

__global__ __launch_bounds__(512, 2) void fused_mlp(const u16* __restrict__ z,
                                                    const u16* __restrict__ w1T,
                                                    const float* __restrict__ b1,
                                                    const u16* __restrict__ w2T,
                                                    const float* __restrict__ b2,
                                                    float* __restrict__ out) {
    __shared__ __align__(16) u16 pool[65536];       // 128 KB
    u16* hc  = pool;                                // [0,65536)  64 KB [128][256]
    u16* sb0 = pool + 32768;                        // 32 KB stage buffer
    u16* sb1 = pool + 49152;                        // 32 KB stage buffer
    const int tid = threadIdx.x;
    const int wid = tid >> 6, lane = tid & 63;
    const int wy = wid >> 2, wx = wid & 3;          // 2 x 4 wave grid
    const int l15 = lane & 15, lsel = lane >> 4;
    const int m0 = blockIdx.x * 128;

    stage32(w1T, 256, sb0, tid);                    // kc0/ks0 w1 tile -> sb0

    f32x4 acc2[4][4] = {};

#pragma unroll 1
    for (int kc = 0; kc < 4; ++kc) {
        // b1 for this kc, loaded EARLY so the compiler's use-wait at the GELU
        // is a counted vmcnt (not a pipeline-draining vmcnt(0)).
        float b1v[4];
#pragma unroll
        for (int n = 0; n < 4; ++n)
            b1v[n] = b1[kc * 256 + wx * 64 + n * 16 + l15];
        asm volatile("" ::: "memory");

        f32x4 acc1[4][4] = {};
        // -------- 4 A-steps: acc1 += z @ w1-tile (z from global) ----------
#pragma unroll
        for (int ks = 0; ks < 4; ++ks) {
            bfrag8 zf[4][2];
#pragma unroll
            for (int m = 0; m < 4; ++m)
#pragma unroll
                for (int kh = 0; kh < 2; ++kh)
                    zf[m][kh] = *(const bfrag8*)(z +
                        (size_t)(m0 + wy * 64 + m * 16 + l15) * 256 +
                        ks * 64 + kh * 32 + lsel * 8);
            if (ks < 3) stage32(w1T + (size_t)(kc * 256) * 256 + (ks + 1) * 64,
                                256, (ks & 1) ? sb0 : sb1, tid);
            else        stage32(w2T + (size_t)kc * 256, 1024, sb0, tid);
            asm volatile("s_waitcnt vmcnt(12)" ::: "memory");
            __builtin_amdgcn_sched_barrier(0);
            __builtin_amdgcn_s_barrier();
            __builtin_amdgcn_sched_barrier(0);
            const u16* cur = (ks & 1) ? sb1 : sb0;
            bfrag8 bf[4][2];
#pragma unroll
            for (int n = 0; n < 4; ++n) {
                const int r = wx * 64 + n * 16 + l15;
#pragma unroll
                for (int kh = 0; kh < 2; ++kh)
                    bf[n][kh] = *(const bfrag8*)(cur + r * 64 +
                                 ((kh * 32 + lsel * 8) ^ ((r & 7) << 3)));
            }
            __builtin_amdgcn_s_setprio(1);
#pragma unroll
            for (int kh = 0; kh < 2; ++kh)
#pragma unroll
                for (int m = 0; m < 4; ++m)
#pragma unroll
                    for (int n = 0; n < 4; ++n)
                        acc1[m][n] = __builtin_amdgcn_mfma_f32_16x16x32_bf16(
                            zf[m][kh], bf[n][kh], acc1[m][n], 0, 0, 0);
            __builtin_amdgcn_s_setprio(0);
            if (ks == 3) {                          // GELU -> hc (swizzled bf16)
#pragma unroll
                for (int m = 0; m < 4; ++m)
#pragma unroll
                    for (int n = 0; n < 4; ++n)
#pragma unroll
                        for (int reg = 0; reg < 4; ++reg) {
                            const int rh = wy * 64 + m * 16 + lsel * 4 + reg;
                            const int ch = wx * 64 + n * 16 + l15;
                            hc[rh * 256 + (ch ^ ((rh & 15) << 3))] =
                                f2u(gelu_fast(acc1[m][n][reg] + b1v[n]));
                        }
                asm volatile("s_waitcnt lgkmcnt(0)" ::: "memory");
                __builtin_amdgcn_sched_barrier(0);  // rule #18 fence
            }
            __builtin_amdgcn_s_barrier();
        }
        // -------- 4 B-steps: acc2 += hc @ w2-tile -------------------------
#pragma unroll
        for (int bs = 0; bs < 4; ++bs) {
            if (bs < 3)
                stage32(w2T + (size_t)kc * 256 + (bs + 1) * 64, 1024,
                        (bs & 1) ? sb0 : sb1, tid);
            else if (kc < 3)
                stage32(w1T + (size_t)((kc + 1) * 256) * 256, 256, sb0, tid);
            if (bs == 3 && kc == 3) {
                asm volatile("s_waitcnt vmcnt(0)" ::: "memory");
            } else {
                asm volatile("s_waitcnt vmcnt(4)" ::: "memory");
            }
            __builtin_amdgcn_sched_barrier(0);
            __builtin_amdgcn_s_barrier();
            __builtin_amdgcn_sched_barrier(0);
            const u16* cur = (bs & 1) ? sb1 : sb0;
            bfrag8 a2[4][2], bb[4][2];
#pragma unroll
            for (int m = 0; m < 4; ++m) {
                const int r = wy * 64 + m * 16 + l15;
#pragma unroll
                for (int kh = 0; kh < 2; ++kh)
                    a2[m][kh] = *(const bfrag8*)(hc + r * 256 +
                        ((bs * 64 + kh * 32 + lsel * 8) ^ ((r & 15) << 3)));
            }
#pragma unroll
            for (int n = 0; n < 4; ++n) {
                const int r = wx * 64 + n * 16 + l15;
#pragma unroll
                for (int kh = 0; kh < 2; ++kh)
                    bb[n][kh] = *(const bfrag8*)(cur + r * 64 +
                                 ((kh * 32 + lsel * 8) ^ ((r & 7) << 3)));
            }
            __builtin_amdgcn_s_setprio(1);
#pragma unroll
            for (int kh = 0; kh < 2; ++kh)
#pragma unroll
                for (int m = 0; m < 4; ++m)
#pragma unroll
                    for (int n = 0; n < 4; ++n)
                        acc2[m][n] = __builtin_amdgcn_mfma_f32_16x16x32_bf16(
                            a2[m][kh], bb[n][kh], acc2[m][n], 0, 0, 0);
            __builtin_amdgcn_s_setprio(0);
            __builtin_amdgcn_s_barrier();
        }
    }

    // ------- final epilogue: out += acc2 + b2, via per-wave LDS transpose -
    // all DMA drained (vmcnt(0)) and all waves past the final barrier.
    float* Ts = (float*)pool + wid * (16 * 68);     // 4352 B per wave
    const int r_ = lane >> 2;                       // row within 16-row strip
    const int cg = (lane & 3) << 4;                 // 16-col group start
#pragma unroll
    for (int m = 0; m < 4; ++m) {
#pragma unroll
        for (int n = 0; n < 4; ++n)
#pragma unroll
            for (int reg = 0; reg < 4; ++reg)
                Ts[(lsel * 4 + reg) * 68 + n * 16 + l15] = acc2[m][n][reg];
        // wave-internal write->read: compiler inserts lgkmcnt wait
        float vals[16];
#pragma unroll
        for (int j = 0; j < 4; ++j)
            *(f32x4*)(vals + 4 * j) = *(const f32x4*)(Ts + r_ * 68 + cg + 4 * j);
        const int gr = m0 + wy * 64 + m * 16 + r_;
        const size_t di = (size_t)gr * 256 + wx * 64 + cg;
#pragma unroll
        for (int j = 0; j < 4; ++j) {
            f32x4 rr  = *(const f32x4*)(out + di + 4 * j);
            f32x4 bb4 = *(const f32x4*)(b2 + wx * 64 + cg + 4 * j);
            f32x4 o;
#pragma unroll
            for (int e = 0; e < 4; ++e)
                o[e] = rr[e] + vals[4 * j + e] + bb4[e];
            *(f32x4*)(out + di + 4 * j) = o;
        }
    }
}

// ------------------------------ attention ----------------------------------
// 4 waves per 256-thread block, one (window,head) per wave, wave-private LDS
// (no barriers). 49 padded to 64. S = q k^T via MFMA from global; softmax
// in-register; P -> LDS (A-layout); O = P V with V transposed in LDS.
__global__ __launch_bounds__(256) void attn_kernel(const u16* __restrict__ q,
                                                   const u16* __restrict__ k,
                                                   const u16* __restrict__ v,
                                                   const float* __restrict__ relb,
                                                   u16* __restrict__ ao) {
    __shared__ __align__(16) u16 PbAll[4][64 * 64];
    __shared__ __align__(16) u16 VtAll[4][32 * 64];
    const int wid = threadIdx.x >> 6;
    const int lane = threadIdx.x & 63;
    u16* Pb = PbAll[wid];
    u16* Vt = VtAll[wid];
    const int bid = blockIdx.x * 4 + wid;
    const int head = bid & 7, win = bid >> 3;
    const int w64 = win & 63;
    const int wr = w64 >> 3, wc = w64 & 7;
    const int l15 = lane & 15, lsel = lane >> 4;
    const size_t base = (size_t)bid * (WS_TOK * 32);
    const u16* qb = q + base;
    const u16* kb = k + base;
    const u16* vb = v + base;

    // stage V transposed: Vt[dim][tok], zero-pad tok 49..63
    for (int idx = lane; idx < WS_TOK * 32; idx += 64) {
        const int tok = idx >> 5, dim = idx & 31;
        Vt[dim * 64 + tok] = vb[idx];
    }
    for (int i = lane; i < 32 * 15; i += 64) {
        const int dim = i / 15, tok = 49 + (i - dim * 15);
        Vt[dim * 64 + tok] = 0;
    }

    bfrag8 qf[4], kf[4];
#pragma unroll
    for (int m = 0; m < 4; ++m) {
        int tok = m * 16 + l15; if (tok > 48) tok = 48;
        qf[m] = *(const bfrag8*)(qb + tok * 32 + lsel * 8);
    }
#pragma unroll
    for (int n = 0; n < 4; ++n) {
        int tok = n * 16 + l15; if (tok > 48) tok = 48;
        kf[n] = *(const bfrag8*)(kb + tok * 32 + lsel * 8);
    }
    f32x4 S[4][4] = {};
#pragma unroll
    for (int m = 0; m < 4; ++m)
#pragma unroll
        for (int n = 0; n < 4; ++n)
            S[m][n] = __builtin_amdgcn_mfma_f32_16x16x32_bf16(qf[m], kf[n], S[m][n], 0, 0, 0);

    // bias + shift-mask + row softmax, write normalized P to LDS
#pragma unroll
    for (int m = 0; m < 4; ++m) {
#pragma unroll
        for (int reg = 0; reg < 4; ++reg) {
            const int row = m * 16 + lsel * 4 + reg;
            const int rowc = row > 48 ? 48 : row;
            const int ih = rowc / 7, iw = rowc - ih * 7;
            const int ri = regionOf(wr * 7 + ih) * 3 + regionOf(wc * 7 + iw);
            float sv[4];
#pragma unroll
            for (int n = 0; n < 4; ++n) {
                const int col = n * 16 + l15;
                float val = S[m][n][reg];
                if (col > 48) {
                    val = -1e30f;
                } else {
                    const int jh = col / 7, jw = col - jh * 7;
                    val += relb[((ih - jh + 6) * 13 + (iw - jw + 6)) * 8 + head];
                    const int rj = regionOf(wr * 7 + jh) * 3 + regionOf(wc * 7 + jw);
                    if (ri != rj) val -= 100.f;
                }
                sv[n] = val;
            }
            float mx = fmaxf(fmaxf(sv[0], sv[1]), fmaxf(sv[2], sv[3]));
#pragma unroll
            for (int off = 1; off < 16; off <<= 1) mx = fmaxf(mx, __shfl_xor(mx, off, 64));
            float p[4], sum = 0.f;
#pragma unroll
            for (int n = 0; n < 4; ++n) { p[n] = __expf(sv[n] - mx); sum += p[n]; }
#pragma unroll
            for (int off = 1; off < 16; off <<= 1) sum += __shfl_xor(sum, off, 64);
            const float inv = 1.f / sum;
#pragma unroll
            for (int n = 0; n < 4; ++n)
                Pb[row * 64 + n * 16 + l15] = f2u(p[n] * inv);
        }
    }
    // wave-private LDS: no barrier needed

    // O = P V
    f32x4 O[4][2] = {};
    bfrag8 vf[2][2];
#pragma unroll
    for (int n = 0; n < 2; ++n) {
        vf[n][0] = *(const bfrag8*)(Vt + (n * 16 + l15) * 64 + lsel * 8);
        vf[n][1] = *(const bfrag8*)(Vt + (n * 16 + l15) * 64 + 32 + lsel * 8);
    }
#pragma unroll
    for (int m = 0; m < 4; ++m) {
        const bfrag8 pf0 = *(const bfrag8*)(Pb + (m * 16 + l15) * 64 + lsel * 8);
        const bfrag8 pf1 = *(const bfrag8*)(Pb + (m * 16 + l15) * 64 + 32 + lsel * 8);
#pragma unroll
        for (int n = 0; n < 2; ++n) {
            O[m][n] = __builtin_amdgcn_mfma_f32_16x16x32_bf16(pf0, vf[n][0], O[m][n], 0, 0, 0);
            O[m][n] = __builtin_amdgcn_mfma_f32_16x16x32_bf16(pf1, vf[n][1], O[m][n], 0, 0, 0);
        }
    }
    const size_t aob = (size_t)win * (WS_TOK * C_DIM) + head * 32;
#pragma unroll
    for (int m = 0; m < 4; ++m) {
#pragma unroll
        for (int reg = 0; reg < 4; ++reg) {
            const int row = m * 16 + lsel * 4 + reg;
            if (row < WS_TOK) {
#pragma unroll
                for (int n = 0; n < 2; ++n)
                    ao[aob + (size_t)row * C_DIM + n * 16 + l15] = f2u(O[m][n][reg]);
            }
        }
    }
}

// ------------------------------ launcher -----------------------------------
extern "C" void kernel_launch(void* const* d_in, const int* in_sizes, int n_in,
                              void* d_out, int out_size, void* d_ws, size_t ws_size,
                              hipStream_t stream) {
    (void)in_sizes; (void)n_in; (void)out_size; (void)ws_size;
    const float* x      = (const float*)d_in[0];
    const float* qkv_w  = (const float*)d_in[1];
    const float* qkv_b  = (const float*)d_in[2];
    const float* proj_w = (const float*)d_in[3];
    const float* proj_b = (const float*)d_in[4];
    const float* relb   = (const float*)d_in[5];
    const float* ln1g   = (const float*)d_in[6];
    const float* ln1b   = (const float*)d_in[7];
    const float* ln2g   = (const float*)d_in[8];
    const float* ln2b   = (const float*)d_in[9];
    const float* w1     = (const float*)d_in[10];
    const float* b1     = (const float*)d_in[11];
    const float* w2     = (const float*)d_in[12];
    const float* b2     = (const float*)d_in[13];
    float* out = (float*)d_out;

    const size_t SZ = (size_t)M_ROWS * C_DIM;      // 25,690,112 elements
    u16* wsu  = (u16*)d_ws;
    u16* xw   = wsu;                                // LN1-windowed input (bf16)
    u16* qq   = wsu + SZ;
    u16* kk   = wsu + 2 * SZ;
    u16* vv   = wsu + 3 * SZ;
    u16* ao   = wsu + 4 * SZ;
    u16* z    = xw;                                 // reuse (xw dead after QKV)
    u16* qkvT = wsu + 5 * SZ;
    u16* projT = qkvT + 256 * 768;
    u16* w1T  = projT + 256 * 256;
    u16* w2T  = w1T + 256 * 1024;

    transpose_k<<<768, 256, 0, stream>>>(qkv_w, qkvT, 256, 768);
    transpose_k<<<256, 256, 0, stream>>>(proj_w, projT, 256, 256);
    transpose_k<<<1024, 256, 0, stream>>>(w1, w1T, 256, 1024);
    transpose_k<<<1024, 256, 0, stream>>>(w2, w2T, 1024, 256);

    ln_kernel<<<M_ROWS / 4, 256, 0, stream>>>(x, ln1g, ln1b, xw, 0);

    gemm_bt<256, 768, 6, 0><<<784 * 6, 256, 0, stream>>>(xw, qkvT, qkv_b,
                                                         qq, kk, vv, nullptr, nullptr);

    attn_kernel<<<N_WIN * 8 / 4, 256, 0, stream>>>(qq, kk, vv, relb, ao);

    gemm_bt<256, 256, 2, 1><<<784 * 2, 256, 0, stream>>>(ao, projT, proj_b,
                                                         nullptr, nullptr, nullptr, out, x);

    ln_kernel<<<M_ROWS / 4, 256, 0, stream>>>(out, ln2g, ln2b, z, 1);

    fused_mlp<<<M_ROWS / 128, 512, 0, stream>>>(z, w1T, b1, w2T, b2, out);
}

// Round 7
// 674.165 us; speedup vs baseline: 1.5559x; 1.5559x over previous
//
#include <hip/hip_runtime.h>

// ---------------------------------------------------------------------------
// Swin block on MI355X. Inputs/outputs f32; internal activations/weights bf16
// (u16), f32 accumulate in MFMA. Round 9: fused MLP reverted to the verified
// R2 pipeline (227us). gemm_bt upgraded: BK=64 (32 MFMA per barrier-pair,
// half the barriers) + XOR-swizzled LDS (kills the 6.4M/dispatch 8-way
// ds_read_b128 conflicts). attn: Vt/Pb XOR swizzles (V-stage write was a
// 32-way conflict; fragment reads 16-way -- attn has no barriers to hide
// them behind).
// ---------------------------------------------------------------------------

typedef unsigned short u16;
typedef __attribute__((ext_vector_type(8))) short bfrag8;     // 8 bf16 = 4 VGPRs
typedef __attribute__((ext_vector_type(8))) unsigned short u16x8;
typedef __attribute__((ext_vector_type(4))) float f32x4;

#define WS_TOK 49
#define C_DIM 256
#define M_ROWS 100352        // 32 * 56 * 56
#define N_WIN 2048           // 32 * 64
#define SCALE_Q 0.17677669529663689f

#if defined(__has_builtin)
#  if __has_builtin(__builtin_amdgcn_global_load_lds)
#    define HAVE_GLL 1
#  endif
#endif
#ifndef HAVE_GLL
#  define HAVE_GLL 0
#endif

__device__ __forceinline__ float u2f(u16 u) {
    union { unsigned int i; float f; } c; c.i = ((unsigned int)u) << 16; return c.f;
}
__device__ __forceinline__ u16 f2u(float f) {
    union { float f; unsigned int i; } c; c.f = f;
    unsigned int i = c.i;
    return (u16)((i + 0x7fffu + ((i >> 16) & 1u)) >> 16);   // RNE
}
__device__ __forceinline__ int regionOf(int h) {           // shift-mask region id
    return h < 49 ? 0 : (h < 53 ? 1 : 2);                  // 0:-7 / -7:-3 / -3:
}
__device__ __forceinline__ float gelu_tanh(float v) {
    const float y = 0.79788456080286536f * (v + 0.044715f * v * v * v);
    const float e = __expf(2.f * y);                        // tanh via one exp
    const float t = 1.f - 2.f / (e + 1.f);
    return 0.5f * v * (1.f + t);
}

__device__ __forceinline__ void g2l16(const u16* g, u16* l) {
#if HAVE_GLL
    __builtin_amdgcn_global_load_lds((const __attribute__((address_space(1))) void*)g,
                                     (__attribute__((address_space(3))) void*)l, 16, 0, 0);
#else
    *(bfrag8*)l = *(const bfrag8*)g;
#endif
}

// --------------------- weight transpose + f32->bf16 cast -------------------
__global__ void transpose_k(const float* __restrict__ in, u16* __restrict__ out,
                            int R, int Ccols) {
    int i = blockIdx.x * 256 + threadIdx.x;
    if (i < R * Ccols) {
        int r = i / Ccols, c = i - r * Ccols;
        out[(size_t)c * R + r] = f2u(in[i]);
    }
}

// ------------- LayerNorm f32->bf16 (mode0: +shift+window gather) -----------
__global__ __launch_bounds__(256) void ln_kernel(const float* __restrict__ xin,
                                                 const float* __restrict__ g,
                                                 const float* __restrict__ b,
                                                 u16* __restrict__ out, int mode) {
    const int w = threadIdx.x >> 6, lane = threadIdx.x & 63;
    const int r = blockIdx.x * 4 + w;   // destination row (windowed order in mode0)
    int s = r;
    if (mode == 0) {
        const int win = r / WS_TOK, tok = r - win * WS_TOK;
        const int b_ = win >> 6, w64 = win & 63;
        const int wr = w64 >> 3, wc = w64 & 7;
        const int th = tok / 7, tw = tok - th * 7;
        int hh = wr * 7 + th + 3; if (hh >= 56) hh -= 56;   // roll(-3) gather
        int ww = wc * 7 + tw + 3; if (ww >= 56) ww -= 56;
        s = b_ * 3136 + hh * 56 + ww;
    }
    const float4 u = *(const float4*)(xin + (size_t)s * C_DIM + lane * 4);
    float f0 = u.x, f1 = u.y, f2 = u.z, f3 = u.w;
    float s1 = f0 + f1 + f2 + f3;
    float s2 = f0 * f0 + f1 * f1 + f2 * f2 + f3 * f3;
#pragma unroll
    for (int off = 32; off; off >>= 1) {
        s1 += __shfl_xor(s1, off, 64);
        s2 += __shfl_xor(s2, off, 64);
    }
    const float mu = s1 * (1.f / 256.f);
    const float rs = rsqrtf(s2 * (1.f / 256.f) - mu * mu + 1e-5f);
    const float4 ug = *(const float4*)(g + lane * 4);
    const float4 ub = *(const float4*)(b + lane * 4);
    ushort4 o;
    o.x = f2u((f0 - mu) * rs * ug.x + ub.x);
    o.y = f2u((f1 - mu) * rs * ug.y + ub.y);
    o.z = f2u((f2 - mu) * rs * ug.z + ub.z);
    o.w = f2u((f3 - mu) * rs * ug.w + ub.w);
    *(ushort4*)(out + (size_t)r * C_DIM + lane * 4) = o;
}

// ------------------------------- GEMM --------------------------------------
// C(M,N) = A(M,K) @ Bt(N,K)^T ; 128x128 tile, BK=64, 4 waves in 2x2.
// 32 MFMA per barrier-pair (was 16 at BK=32). LDS 32KB, XOR-swizzled:
// staging source-preswizzles seg s^(row&7); fragment reads XOR the same ->
// 2 lanes/bank (free) instead of 8-way conflicts.
// Epilogue: per-wave LDS transpose (stride 68 floats) -> coalesced stores.
// EPI 0: qkv scatter (bf16)  1: proj+reverse+residual (f32)
template <int KD, int ND, int NY, int EPI>
__global__ __launch_bounds__(256) void gemm_bt(const u16* __restrict__ A,
                                               const u16* __restrict__ Bt,
                                               const float* __restrict__ bias,
                                               u16* __restrict__ o0,
                                               u16* __restrict__ o1,
                                               u16* __restrict__ o2,
                                               float* __restrict__ fo,
                                               const float* __restrict__ res) {
    __shared__ __align__(16) char pool[32768];      // As(16K)+Bs(16K) / Ts(17408)
    u16* As = (u16*)pool;
    u16* Bs = (u16*)(pool + 16384);
    const int tid = threadIdx.x;
    const int bid = blockIdx.x;
    const int m0 = (bid / NY) * 128;
    const int n0 = (bid % NY) * 128;
    const int wid = tid >> 6, lane = tid & 63;
    const int wy = wid >> 1, wx = wid & 1;
    const int l15 = lane & 15, lsel = lane >> 4;

    f32x4 acc[4][4] = {};
    const u16* Ag = A + (size_t)m0 * KD;
    const u16* Bg = Bt + (size_t)n0 * KD;

    for (int k0 = 0; k0 < KD; k0 += 64) {
#pragma unroll
        for (int p = 0; p < 4; ++p) {               // 128 rows x 8 segs of 8 u16
            const int idx = p * 256 + tid;
            const int row = idx >> 3, s = idx & 7;
            const int so = (s ^ (row & 7)) << 3;    // source-preswizzled seg
            g2l16(Ag + (size_t)row * KD + k0 + so, As + idx * 8);
            g2l16(Bg + (size_t)row * KD + k0 + so, Bs + idx * 8);
        }
        __syncthreads();
#pragma unroll
        for (int kh = 0; kh < 2; ++kh) {
            bfrag8 af[4], bfv[4];
#pragma unroll
            for (int m = 0; m < 4; ++m) {
                const int r = wy * 64 + m * 16 + l15;
                af[m] = *(const bfrag8*)(As + r * 64 +
                         ((kh * 32 + lsel * 8) ^ ((r & 7) << 3)));
            }
#pragma unroll
            for (int n = 0; n < 4; ++n) {
                const int r = wx * 64 + n * 16 + l15;
                bfv[n] = *(const bfrag8*)(Bs + r * 64 +
                          ((kh * 32 + lsel * 8) ^ ((r & 7) << 3)));
            }
#pragma unroll
            for (int m = 0; m < 4; ++m)
#pragma unroll
                for (int n = 0; n < 4; ++n)
                    acc[m][n] = __builtin_amdgcn_mfma_f32_16x16x32_bf16(
                        af[m], bfv[n], acc[m][n], 0, 0, 0);
        }
        __syncthreads();
    }

    // ---------------- epilogue: per-wave LDS transpose ----------------
    float* Ts = (float*)pool + wid * (16 * 68);     // 4352 B per wave
    const int r  = lane >> 2;                       // output row within strip
    const int cg = (lane & 3) << 4;                 // 16-col group start

#pragma unroll
    for (int m = 0; m < 4; ++m) {
#pragma unroll
        for (int n = 0; n < 4; ++n)
#pragma unroll
            for (int reg = 0; reg < 4; ++reg)
                Ts[(lsel * 4 + reg) * 68 + n * 16 + l15] = acc[m][n][reg];
        // wave-internal write->read: compiler inserts lgkmcnt wait
        float vals[16];
#pragma unroll
        for (int j = 0; j < 4; ++j)
            *(f32x4*)(vals + 4 * j) = *(const f32x4*)(Ts + r * 68 + cg + 4 * j);

        const int gr  = m0 + wy * 64 + m * 16 + r;
        const int gc0 = n0 + wx * 64 + cg;
        float bias16[16];
#pragma unroll
        for (int j = 0; j < 4; ++j)
            *(f32x4*)(bias16 + 4 * j) = *(const f32x4*)(bias + gc0 + 4 * j);

        if (EPI == 0) {
            const int win = gr / WS_TOK, tok = gr - win * WS_TOK;
            const int part = gc0 >> 8, head = (gc0 >> 5) & 7, hd = gc0 & 31;
            u16* dst = (part == 0) ? o0 : (part == 1) ? o1 : o2;
            const float sc = (part == 0) ? SCALE_Q : 1.f;
            const size_t di = (size_t)win * 8 * (WS_TOK * 32) + (size_t)tok * 32 +
                              (size_t)head * (WS_TOK * 32) + hd;
            u16x8 pk[2];
#pragma unroll
            for (int j = 0; j < 16; ++j)
                ((u16*)pk)[j] = f2u((vals[j] + bias16[j]) * sc);
            *(u16x8*)(dst + di)     = pk[0];
            *(u16x8*)(dst + di + 8) = pk[1];
        } else if (EPI == 1) {
            const int win = gr / WS_TOK, tok = gr - win * WS_TOK;
            const int b_ = win >> 6, w64 = win & 63;
            const int wr = w64 >> 3, wc = w64 & 7;
            const int th = tok / 7, tw = tok - th * 7;
            int hh = wr * 7 + th + 3; if (hh >= 56) hh -= 56;  // roll(+3) scatter
            int ww = wc * 7 + tw + 3; if (ww >= 56) ww -= 56;
            const size_t di = ((size_t)b_ * 3136 + hh * 56 + ww) * C_DIM + gc0;
#pragma unroll
            for (int j = 0; j < 4; ++j) {
                f32x4 rr = *(const f32x4*)(res + di + 4 * j);
                f32x4 o;
#pragma unroll
                for (int e = 0; e < 4; ++e)
                    o[e] = rr[e] + vals[4 * j + e] + bias16[4 * j + e];
                *(f32x4*)(fo + di + 4 * j) = o;
            }
        } else if (EPI == 2) {
            u16x8 pk[2];
#pragma unroll
            for (int j = 0; j < 16; ++j)
                ((u16*)pk)[j] = f2u(gelu_tanh(vals[j] + bias16[j]));
            u16* dst = o0 + (size_t)gr * ND + gc0;
            *(u16x8*)dst       = pk[0];
            *(u16x8*)(dst + 8) = pk[1];
        } else {
            const size_t di = (size_t)gr * ND + gc0;
#pragma unroll
            for (int j = 0; j < 4; ++j) {
                f32x4 rr = *(const f32x4*)(res + di + 4 * j);
                f32x4 o;
#pragma unroll
                for (int e = 0; e < 4; ++e)
                    o[e] = rr[e] + vals[4 * j + e] + bias16[4 * j + e];
                *(f32x4*)(fo + di + 4 * j) = o;
            }
        }
    }
}

// --------------------------- fused MLP (R2-verified) -----------------------
// out += GELU(z @ w1T^T + b1) @ w2T^T + b2; h never leaves LDS. Measured
// 227us (Round 2). M-tile 64 rows, 4 waves (2x2). z persistent in LDS.
// Stage next 16KB tile into alternate buffer BEFORE the MFMAs, one
// __syncthreads per step. LDS 80KB -> 2 blocks/CU.
__device__ __forceinline__ void stage_w1t(const u16* __restrict__ w1T, u16* dst,
                                          int kc, int k0, int tid) {
#pragma unroll
    for (int p = 0; p < 4; ++p) {                   // [128 hcols][64 k] = 16KB
        const int i = p * 256 + tid;
        const int row = i >> 3, s = i & 7;
        g2l16(w1T + (size_t)(kc * 128 + row) * 256 + k0 + ((s ^ (row & 7)) << 3),
              dst + i * 8);
    }
}
__device__ __forceinline__ void stage_w2t(const u16* __restrict__ w2T, u16* dst,
                                          int kc, int bs, int tid) {
#pragma unroll
    for (int p = 0; p < 4; ++p) {                   // [256 outcols][32 k] = 16KB
        const int i = p * 256 + tid;
        const int row = i >> 2, s = i & 3;
        g2l16(w2T + (size_t)row * 1024 + kc * 128 + bs * 32 +
                  ((s ^ ((row >> 1) & 3)) << 3),
              dst + i * 8);
    }
}

__global__ __launch_bounds__(256, 2) void fused_mlp(const u16* __restrict__ z,
                                                    const u16* __restrict__ w1T,
                                                    const float* __restrict__ b1,
                                                    const u16* __restrict__ w2T,
                                                    const float* __restrict__ b2,
                                                    float* __restrict__ out) {
    __shared__ __align__(16) u16 pool[40960];       // 80 KB
    u16* zS  = pool;                                // [0,16384)  32 KB persistent
    u16* wb0 = pool + 16384;                        // 16 KB stage buffer A
    u16* wb1 = pool + 24576;                        // 16 KB stage buffer B
    u16* hc  = pool + 32768;                        // 16 KB h-chunk
    const int tid = threadIdx.x;
    const int wid = tid >> 6, lane = tid & 63;
    const int wy = wid >> 1, wx = wid & 1;
    const int l15 = lane & 15, lsel = lane >> 4;
    const int m0 = blockIdx.x * 64;

    // one-time z stage: [64 rows][256 k], source pre-swizzled (seg ^ row&7)
#pragma unroll
    for (int p = 0; p < 8; ++p) {
        const int i = p * 256 + tid;
        const int row = i >> 5, s = i & 31;
        g2l16(z + (size_t)(m0 + row) * 256 + ((s ^ (row & 7)) << 3), zS + i * 8);
    }
    stage_w1t(w1T, wb0, 0, 0, tid);                 // prologue: first w1 tile
    __syncthreads();

    f32x4 acc2[2][8] = {};

    for (int kc = 0; kc < 8; ++kc) {
        float b1v[4];
#pragma unroll
        for (int n = 0; n < 4; ++n)
            b1v[n] = b1[kc * 128 + wx * 64 + n * 16 + l15];

        f32x4 acc1[2][4] = {};
        // ---------------- 4 A-steps: acc1 += zS @ w1-tile -----------------
#pragma unroll
        for (int ks = 0; ks < 4; ++ks) {
            u16* wc = (ks & 1) ? wb1 : wb0;
            u16* wn = (ks & 1) ? wb0 : wb1;
            if (ks < 3) stage_w1t(w1T, wn, kc, (ks + 1) * 64, tid);
            else        stage_w2t(w2T, wn, kc, 0, tid);
#pragma unroll
            for (int sub = 0; sub < 2; ++sub) {
                bfrag8 af[2], bf[4];
#pragma unroll
                for (int m = 0; m < 2; ++m) {
                    const int r = wy * 32 + m * 16 + l15;
                    af[m] = *(const bfrag8*)(zS + r * 256 +
                             ((ks * 64 + sub * 32 + lsel * 8) ^ ((r & 7) << 3)));
                }
#pragma unroll
                for (int n = 0; n < 4; ++n) {
                    const int r = wx * 64 + n * 16 + l15;
                    bf[n] = *(const bfrag8*)(wc + r * 64 +
                             ((sub * 32 + lsel * 8) ^ ((r & 7) << 3)));
                }
#pragma unroll
                for (int m = 0; m < 2; ++m)
#pragma unroll
                    for (int n = 0; n < 4; ++n)
                        acc1[m][n] = __builtin_amdgcn_mfma_f32_16x16x32_bf16(
                            af[m], bf[n], acc1[m][n], 0, 0, 0);
            }
            if (ks == 3) {                          // GELU -> hc (swizzled bf16)
#pragma unroll
                for (int m = 0; m < 2; ++m)
#pragma unroll
                    for (int n = 0; n < 4; ++n)
#pragma unroll
                        for (int reg = 0; reg < 4; ++reg) {
                            const int rh = wy * 32 + m * 16 + lsel * 4 + reg;
                            const int ch = wx * 64 + n * 16 + l15;
                            hc[rh * 128 + (ch ^ ((rh & 15) << 3))] =
                                f2u(gelu_tanh(acc1[m][n][reg] + b1v[n]));
                        }
            }
            __syncthreads();
        }
        // ---------------- 4 B-steps: acc2 += hc @ w2-tile -----------------
#pragma unroll
        for (int bs = 0; bs < 4; ++bs) {
            u16* wc = (bs & 1) ? wb1 : wb0;
            u16* wn = (bs & 1) ? wb0 : wb1;
            if (bs < 3)      stage_w2t(w2T, wn, kc, bs + 1, tid);
            else if (kc < 7) stage_w1t(w1T, wn, kc + 1, 0, tid);
            bfrag8 a2[2], bb[8];
#pragma unroll
            for (int m = 0; m < 2; ++m) {
                const int r = wy * 32 + m * 16 + l15;
                a2[m] = *(const bfrag8*)(hc + r * 128 +
                         ((bs * 32 + lsel * 8) ^ ((r & 15) << 3)));
            }
#pragma unroll
            for (int n = 0; n < 8; ++n) {
                const int r = wx * 128 + n * 16 + l15;
                bb[n] = *(const bfrag8*)(wc + r * 32 +
                         ((lsel * 8) ^ (((r >> 1) & 3) << 3)));
            }
#pragma unroll
            for (int m = 0; m < 2; ++m)
#pragma unroll
                for (int n = 0; n < 8; ++n)
                    acc2[m][n] = __builtin_amdgcn_mfma_f32_16x16x32_bf16(
                        a2[m], bb[n], acc2[m][n], 0, 0, 0);
            __syncthreads();
        }
    }

    // ---------------- final epilogue: out += acc2 + b2 (in place) ---------
    float b2v[8];
#pragma unroll
    for (int n = 0; n < 8; ++n)
        b2v[n] = b2[wx * 128 + n * 16 + l15];
#pragma unroll
    for (int m = 0; m < 2; ++m)
#pragma unroll
        for (int reg = 0; reg < 4; ++reg) {
            const int row = m0 + wy * 32 + m * 16 + lsel * 4 + reg;
#pragma unroll
            for (int n = 0; n < 8; ++n) {
                const size_t di = (size_t)row * 256 + wx * 128 + n * 16 + l15;
                out[di] += acc2[m][n][reg] + b2v[n];
            }
        }
}

// ------------------------------ attention ----------------------------------
// 4 waves per 256-thread block, one (window,head) per wave, wave-private LDS
// (no barriers). 49 padded to 64. Vt and Pb XOR-swizzled: attn has no
// barriers, so its LDS conflicts (32-way V-stage writes, 16-way fragment
// reads at 128B row stride) sit directly on the critical path.
__global__ __launch_bounds__(256) void attn_kernel(const u16* __restrict__ q,
                                                   const u16* __restrict__ k,
                                                   const u16* __restrict__ v,
                                                   const float* __restrict__ relb,
                                                   u16* __restrict__ ao) {
    __shared__ __align__(16) u16 PbAll[4][64 * 64];
    __shared__ __align__(16) u16 VtAll[4][32 * 64];
    const int wid = threadIdx.x >> 6;
    const int lane = threadIdx.x & 63;
    u16* Pb = PbAll[wid];
    u16* Vt = VtAll[wid];
    const int bid = blockIdx.x * 4 + wid;
    const int head = bid & 7, win = bid >> 3;
    const int w64 = win & 63;
    const int wr = w64 >> 3, wc = w64 & 7;
    const int l15 = lane & 15, lsel = lane >> 4;
    const size_t base = (size_t)bid * (WS_TOK * 32);
    const u16* qb = q + base;
    const u16* kb = k + base;
    const u16* vb = v + base;

    // stage V transposed: Vt[dim][tok^((dim&7)<<3)], zero-pad tok 49..63
    for (int idx = lane; idx < WS_TOK * 32; idx += 64) {
        const int tok = idx >> 5, dim = idx & 31;
        Vt[dim * 64 + (tok ^ ((dim & 7) << 3))] = vb[idx];
    }
    for (int i = lane; i < 32 * 15; i += 64) {
        const int dim = i / 15, tok = 49 + (i - dim * 15);
        Vt[dim * 64 + (tok ^ ((dim & 7) << 3))] = 0;
    }

    bfrag8 qf[4], kf[4];
#pragma unroll
    for (int m = 0; m < 4; ++m) {
        int tok = m * 16 + l15; if (tok > 48) tok = 48;
        qf[m] = *(const bfrag8*)(qb + tok * 32 + lsel * 8);
    }
#pragma unroll
    for (int n = 0; n < 4; ++n) {
        int tok = n * 16 + l15; if (tok > 48) tok = 48;
        kf[n] = *(const bfrag8*)(kb + tok * 32 + lsel * 8);
    }
    f32x4 S[4][4] = {};
#pragma unroll
    for (int m = 0; m < 4; ++m)
#pragma unroll
        for (int n = 0; n < 4; ++n)
            S[m][n] = __builtin_amdgcn_mfma_f32_16x16x32_bf16(qf[m], kf[n], S[m][n], 0, 0, 0);

    // bias + shift-mask + row softmax, write normalized P to LDS (swizzled)
#pragma unroll
    for (int m = 0; m < 4; ++m) {
#pragma unroll
        for (int reg = 0; reg < 4; ++reg) {
            const int row = m * 16 + lsel * 4 + reg;
            const int rowc = row > 48 ? 48 : row;
            const int ih = rowc / 7, iw = rowc - ih * 7;
            const int ri = regionOf(wr * 7 + ih) * 3 + regionOf(wc * 7 + iw);
            float sv[4];
#pragma unroll
            for (int n = 0; n < 4; ++n) {
                const int col = n * 16 + l15;
                float val = S[m][n][reg];
                if (col > 48) {
                    val = -1e30f;
                } else {
                    const int jh = col / 7, jw = col - jh * 7;
                    val += relb[((ih - jh + 6) * 13 + (iw - jw + 6)) * 8 + head];
                    const int rj = regionOf(wr * 7 + jh) * 3 + regionOf(wc * 7 + jw);
                    if (ri != rj) val -= 100.f;
                }
                sv[n] = val;
            }
            float mx = fmaxf(fmaxf(sv[0], sv[1]), fmaxf(sv[2], sv[3]));
#pragma unroll
            for (int off = 1; off < 16; off <<= 1) mx = fmaxf(mx, __shfl_xor(mx, off, 64));
            float p[4], sum = 0.f;
#pragma unroll
            for (int n = 0; n < 4; ++n) { p[n] = __expf(sv[n] - mx); sum += p[n]; }
#pragma unroll
            for (int off = 1; off < 16; off <<= 1) sum += __shfl_xor(sum, off, 64);
            const float inv = 1.f / sum;
#pragma unroll
            for (int n = 0; n < 4; ++n)
                Pb[row * 64 + ((n * 16 + l15) ^ ((row & 7) << 3))] = f2u(p[n] * inv);
        }
    }
    // wave-private LDS: no barrier needed

    // O = P V
    f32x4 O[4][2] = {};
    bfrag8 vf[2][2];
#pragma unroll
    for (int n = 0; n < 2; ++n) {
        const int r = n * 16 + l15;
        vf[n][0] = *(const bfrag8*)(Vt + r * 64 + ((lsel * 8) ^ ((r & 7) << 3)));
        vf[n][1] = *(const bfrag8*)(Vt + r * 64 + ((32 + lsel * 8) ^ ((r & 7) << 3)));
    }
#pragma unroll
    for (int m = 0; m < 4; ++m) {
        const int r = m * 16 + l15;
        const bfrag8 pf0 = *(const bfrag8*)(Pb + r * 64 +
                            ((lsel * 8) ^ ((r & 7) << 3)));
        const bfrag8 pf1 = *(const bfrag8*)(Pb + r * 64 +
                            ((32 + lsel * 8) ^ ((r & 7) << 3)));
#pragma unroll
        for (int n = 0; n < 2; ++n) {
            O[m][n] = __builtin_amdgcn_mfma_f32_16x16x32_bf16(pf0, vf[n][0], O[m][n], 0, 0, 0);
            O[m][n] = __builtin_amdgcn_mfma_f32_16x16x32_bf16(pf1, vf[n][1], O[m][n], 0, 0, 0);
        }
    }
    const size_t aob = (size_t)win * (WS_TOK * C_DIM) + head * 32;
#pragma unroll
    for (int m = 0; m < 4; ++m) {
#pragma unroll
        for (int reg = 0; reg < 4; ++reg) {
            const int row = m * 16 + lsel * 4 + reg;
            if (row < WS_TOK) {
#pragma unroll
                for (int n = 0; n < 2; ++n)
                    ao[aob + (size_t)row * C_DIM + n * 16 + l15] = f2u(O[m][n][reg]);
            }
        }
    }
}

// ------------------------------ launcher -----------------------------------
extern "C" void kernel_launch(void* const* d_in, const int* in_sizes, int n_in,
                              void* d_out, int out_size, void* d_ws, size_t ws_size,
                              hipStream_t stream) {
    (void)in_sizes; (void)n_in; (void)out_size; (void)ws_size;
    const float* x      = (const float*)d_in[0];
    const float* qkv_w  = (const float*)d_in[1];
    const float* qkv_b  = (const float*)d_in[2];
    const float* proj_w = (const float*)d_in[3];
    const float* proj_b = (const float*)d_in[4];
    const float* relb   = (const float*)d_in[5];
    const float* ln1g   = (const float*)d_in[6];
    const float* ln1b   = (const float*)d_in[7];
    const float* ln2g   = (const float*)d_in[8];
    const float* ln2b   = (const float*)d_in[9];
    const float* w1     = (const float*)d_in[10];
    const float* b1     = (const float*)d_in[11];
    const float* w2     = (const float*)d_in[12];
    const float* b2     = (const float*)d_in[13];
    float* out = (float*)d_out;

    const size_t SZ = (size_t)M_ROWS * C_DIM;      // 25,690,112 elements
    u16* wsu  = (u16*)d_ws;
    u16* xw   = wsu;                                // LN1-windowed input (bf16)
    u16* qq   = wsu + SZ;
    u16* kk   = wsu + 2 * SZ;
    u16* vv   = wsu + 3 * SZ;
    u16* ao   = wsu + 4 * SZ;
    u16* z    = xw;                                 // reuse (xw dead after QKV)
    u16* qkvT = wsu + 5 * SZ;
    u16* projT = qkvT + 256 * 768;
    u16* w1T  = projT + 256 * 256;
    u16* w2T  = w1T + 256 * 1024;

    transpose_k<<<768, 256, 0, stream>>>(qkv_w, qkvT, 256, 768);
    transpose_k<<<256, 256, 0, stream>>>(proj_w, projT, 256, 256);
    transpose_k<<<1024, 256, 0, stream>>>(w1, w1T, 256, 1024);
    transpose_k<<<1024, 256, 0, stream>>>(w2, w2T, 1024, 256);

    ln_kernel<<<M_ROWS / 4, 256, 0, stream>>>(x, ln1g, ln1b, xw, 0);

    gemm_bt<256, 768, 6, 0><<<784 * 6, 256, 0, stream>>>(xw, qkvT, qkv_b,
                                                         qq, kk, vv, nullptr, nullptr);

    attn_kernel<<<N_WIN * 8 / 4, 256, 0, stream>>>(qq, kk, vv, relb, ao);

    gemm_bt<256, 256, 2, 1><<<784 * 2, 256, 0, stream>>>(ao, projT, proj_b,
                                                         nullptr, nullptr, nullptr, out, x);

    ln_kernel<<<M_ROWS / 4, 256, 0, stream>>>(out, ln2g, ln2b, z, 1);

    fused_mlp<<<M_ROWS / 64, 256, 0, stream>>>(z, w1T, b1, w2T, b2, out);
}